// Round 1
// baseline (411.116 us; speedup 1.0000x reference)
//
#include <hip/hip_runtime.h>
#include <hip/hip_bf16.h>

// SiLU forward: out = x * sigmoid(x) = x / (1 + exp(-x))
// Input: float32, 4*4096*4096 = 67,108,864 elements (divisible by 4).
// Memory-bound elementwise op -> float4 vectorization, direct index mapping.

__global__ __launch_bounds__(256) void silu_f32x4_kernel(const float4* __restrict__ x,
                                                         float4* __restrict__ out,
                                                         int n4) {
    int i = blockIdx.x * blockDim.x + threadIdx.x;
    if (i >= n4) return;
    float4 v = x[i];
    float4 r;
    r.x = v.x / (1.0f + __expf(-v.x));
    r.y = v.y / (1.0f + __expf(-v.y));
    r.z = v.z / (1.0f + __expf(-v.z));
    r.w = v.w / (1.0f + __expf(-v.w));
    out[i] = r;
}

extern "C" void kernel_launch(void* const* d_in, const int* in_sizes, int n_in,
                              void* d_out, int out_size, void* d_ws, size_t ws_size,
                              hipStream_t stream) {
    const float* x = (const float*)d_in[0];
    float* out = (float*)d_out;
    int n = in_sizes[0];           // 67,108,864
    int n4 = n / 4;                // 16,777,216 (n is divisible by 4)

    const int block = 256;
    int grid = (n4 + block - 1) / block;   // 65,536 blocks

    silu_f32x4_kernel<<<grid, block, 0, stream>>>(
        (const float4*)x, (float4*)out, n4);
}